// Round 4
// baseline (4396.895 us; speedup 1.0000x reference)
//
#include <hip/hip_runtime.h>
#include <hip/hip_bf16.h>

#define NH 12
#define HD 64
#define DM 768
#define SEQ 1024
#define BATCH 8

// ---------------------------------------------------------------------------
// QKV projection: out[i,o] = sum_d X[i,d] * W[o,d] + bias[o]   (q = x@wq.T+bq)
// X flattened [8192][768]. 64x64 tile, 256 threads, 4x4 per thread. All fp32.
// ---------------------------------------------------------------------------
__global__ __launch_bounds__(256) void qkv_gemm(
    const float* __restrict__ x,
    const float* __restrict__ wq, const float* __restrict__ bq,
    const float* __restrict__ wk, const float* __restrict__ bk,
    const float* __restrict__ wv, const float* __restrict__ bv,
    float* __restrict__ qo, float* __restrict__ ko, float* __restrict__ vo)
{
    const float* w; const float* bias; float* out;
    if (blockIdx.z == 0)      { w = wq; bias = bq; out = qo; }
    else if (blockIdx.z == 1) { w = wk; bias = bk; out = ko; }
    else                      { w = wv; bias = bv; out = vo; }

    __shared__ float Xs[64][17];
    __shared__ float Ws[64][17];

    const int row0 = blockIdx.x * 64;   // token rows (0..8191)
    const int col0 = blockIdx.y * 64;   // output features (0..767)
    const int tid  = threadIdx.x;
    const int tr = tid >> 4;
    const int tc = tid & 15;

    float acc[4][4] = {};

    for (int k0 = 0; k0 < DM; k0 += 16) {
        #pragma unroll
        for (int u = 0; u < 4; ++u) {
            int e = tid + 256 * u;            // 0..1023
            int r = e >> 4, c = e & 15;
            Xs[r][c] = x[(size_t)(row0 + r) * DM + k0 + c];
            Ws[r][c] = w[(size_t)(col0 + r) * DM + k0 + c];
        }
        __syncthreads();
        #pragma unroll
        for (int kk = 0; kk < 16; ++kk) {
            float a[4], b[4];
            #pragma unroll
            for (int i = 0; i < 4; ++i) a[i] = Xs[tr * 4 + i][kk];
            #pragma unroll
            for (int j = 0; j < 4; ++j) b[j] = Ws[tc * 4 + j][kk];
            #pragma unroll
            for (int i = 0; i < 4; ++i)
                #pragma unroll
                for (int j = 0; j < 4; ++j)
                    acc[i][j] += a[i] * b[j];
        }
        __syncthreads();
    }

    #pragma unroll
    for (int i = 0; i < 4; ++i) {
        int r = row0 + tr * 4 + i;
        #pragma unroll
        for (int j = 0; j < 4; ++j) {
            int c = col0 + tc * 4 + j;
            out[(size_t)r * DM + c] = acc[i][j] + bias[c];
        }
    }
}

// ---------------------------------------------------------------------------
// Attention: block = (16-row i-tile, head, batch).
// S[i,j] = q_i . (k_j + dist_emb[i-j+1023]); softmax(S * 1/8); O = P @ V.
// Output is FP32 (reference output dtype).
// ---------------------------------------------------------------------------
__global__ __launch_bounds__(256) void attn_kernel(
    const float* __restrict__ qws,
    const float* __restrict__ kws,
    const float* __restrict__ vws,
    const float* __restrict__ demb,  // [2047][64]
    float* __restrict__ out)
{
    const int i0 = blockIdx.x * 16;
    const int h  = blockIdx.y;
    const int b  = blockIdx.z;
    const int tid = threadIdx.x;
    const size_t rowbase = (size_t)b * SEQ;

    __shared__ float S[16][1024];     // 64 KB scores -> probabilities
    __shared__ float Qs[16][64];
    __shared__ float Kt[64][65];      // K chunk, reused for V chunk
    __shared__ float De[79][65];      // dist_emb window
    __shared__ float red[16][17];
    __shared__ float smInv[16];

    for (int e = tid; e < 16 * 64; e += 256) {
        int r = e >> 6, c = e & 63;
        Qs[r][c] = qws[(rowbase + i0 + r) * DM + h * HD + c];
    }

    // ---- score phase: 16 chunks of 64 key columns ----
    for (int jc = 0; jc < SEQ; jc += 64) {
        __syncthreads();   // protect Kt/De reuse; covers Qs on iter 0
        for (int e = tid; e < 64 * 64; e += 256) {
            int r = e >> 6, c = e & 63;
            Kt[r][c] = kws[(rowbase + jc + r) * DM + h * HD + c];
        }
        const int base = i0 - jc + 960;   // demb row = base + (il - jl + 63)
        for (int e = tid; e < 79 * 64; e += 256) {
            int r = e >> 6, c = e & 63;
            De[r][c] = demb[(size_t)(base + r) * HD + c];
        }
        __syncthreads();
        #pragma unroll
        for (int u = 0; u < 4; ++u) {
            int pe = tid + 256 * u;       // 0..1023
            int il = pe >> 6;             // 0..15
            int jl = pe & 63;             // 0..63
            const float* qrow = Qs[il];
            const float* krow = Kt[jl];
            const float* drow = De[il - jl + 63];
            float acc = 0.f;
            #pragma unroll 8
            for (int d = 0; d < 64; ++d)
                acc += qrow[d] * (krow[d] + drow[d]);
            S[il][jc + jl] = acc;
        }
    }
    __syncthreads();

    // ---- softmax (scale AFTER bias add, factor 1/8) ----
    {
        const int row = tid >> 4;
        const int l   = tid & 15;
        float m = -1e30f;
        for (int j = l; j < SEQ; j += 16) m = fmaxf(m, S[row][j]);
        red[row][l] = m;
        __syncthreads();
        if (l == 0) {
            float mm = red[row][0];
            for (int t = 1; t < 16; ++t) mm = fmaxf(mm, red[row][t]);
            red[row][16] = mm;
        }
        __syncthreads();
        m = red[row][16];
        float sum = 0.f;
        for (int j = l; j < SEQ; j += 16) {
            float p = __expf((S[row][j] - m) * 0.125f);
            S[row][j] = p;
            sum += p;
        }
        red[row][l] = sum;
        __syncthreads();
        if (l == 0) {
            float s = 0.f;
            for (int t = 0; t < 16; ++t) s += red[row][t];
            smInv[row] = 1.0f / s;
        }
    }

    // ---- PV phase ----
    const int d  = tid & 63;
    const int rg = tid >> 6;            // 0..3 (4 rows each)
    float acc[4] = {0.f, 0.f, 0.f, 0.f};
    for (int jc = 0; jc < SEQ; jc += 64) {
        __syncthreads();   // protect Kt reuse; covers S/smInv on iter 0
        for (int e = tid; e < 64 * 64; e += 256) {
            int r = e >> 6, c = e & 63;
            Kt[r][c] = vws[(rowbase + jc + r) * DM + h * HD + c];
        }
        __syncthreads();
        for (int j = 0; j < 64; ++j) {
            float vv = Kt[j][d];
            #pragma unroll
            for (int rr = 0; rr < 4; ++rr)
                acc[rr] += S[rg * 4 + rr][jc + j] * vv;
        }
    }

    #pragma unroll
    for (int rr = 0; rr < 4; ++rr) {
        int i = i0 + rg * 4 + rr;
        out[(rowbase + i) * DM + h * HD + d] = acc[rr] * smInv[rg * 4 + rr];
    }
}

// ---------------------------------------------------------------------------
extern "C" void kernel_launch(void* const* d_in, const int* in_sizes, int n_in,
                              void* d_out, int out_size, void* d_ws, size_t ws_size,
                              hipStream_t stream) {
    const float* x  = (const float*)d_in[0];
    const float* wq = (const float*)d_in[1];
    const float* bq = (const float*)d_in[2];
    const float* wk = (const float*)d_in[3];
    const float* bk = (const float*)d_in[4];
    const float* wv = (const float*)d_in[5];
    const float* bv = (const float*)d_in[6];
    const float* de = (const float*)d_in[7];
    float* out = (float*)d_out;   // reference output dtype is FP32

    float* ws  = (float*)d_ws;
    float* qws = ws;
    float* kws = ws + (size_t)BATCH * SEQ * DM;
    float* vws = ws + (size_t)2 * BATCH * SEQ * DM;

    qkv_gemm<<<dim3(128, 12, 3), 256, 0, stream>>>(x, wq, bq, wk, bk, wv, bv,
                                                   qws, kws, vws);
    attn_kernel<<<dim3(64, NH, BATCH), 256, 0, stream>>>(qws, kws, vws, de, out);
}

// Round 5
// 1299.234 us; speedup vs baseline: 3.3842x; 3.3842x over previous
//
#include <hip/hip_runtime.h>
#include <hip/hip_bf16.h>

#define NH 12
#define HD 64
#define DM 768
#define SEQ 1024
#define BATCH 8

typedef __attribute__((ext_vector_type(8))) short bf16x8;
typedef __attribute__((ext_vector_type(4))) float f32x4;

__device__ __forceinline__ short f2b(float x) {
    unsigned u = __float_as_uint(x);
    u += 0x7fffu + ((u >> 16) & 1u);    // RNE to bf16 (finite values)
    return (short)(u >> 16);
}

// pack 8 consecutive f32 (global or LDS) into a bf16x8 MFMA fragment
__device__ __forceinline__ bf16x8 pack8(const float* p) {
    f32x4 a = *(const f32x4*)(p);
    f32x4 b = *(const f32x4*)(p + 4);
    bf16x8 r;
    r[0] = f2b(a[0]); r[1] = f2b(a[1]); r[2] = f2b(a[2]); r[3] = f2b(a[3]);
    r[4] = f2b(b[0]); r[5] = f2b(b[1]); r[6] = f2b(b[2]); r[7] = f2b(b[3]);
    return r;
}

#define MFMA(A, B, C) __builtin_amdgcn_mfma_f32_16x16x32_bf16(A, B, C, 0, 0, 0)

// ---------------------------------------------------------------------------
// QKV projection (fp32, unchanged from round 4). V goes to vo (= d_out scratch).
// ---------------------------------------------------------------------------
__global__ __launch_bounds__(256) void qkv_gemm(
    const float* __restrict__ x,
    const float* __restrict__ wq, const float* __restrict__ bq,
    const float* __restrict__ wk, const float* __restrict__ bk,
    const float* __restrict__ wv, const float* __restrict__ bv,
    float* __restrict__ qo, float* __restrict__ ko, float* __restrict__ vo)
{
    const float* w; const float* bias; float* out;
    if (blockIdx.z == 0)      { w = wq; bias = bq; out = qo; }
    else if (blockIdx.z == 1) { w = wk; bias = bk; out = ko; }
    else                      { w = wv; bias = bv; out = vo; }

    __shared__ float Xs[64][17];
    __shared__ float Ws[64][17];

    const int row0 = blockIdx.x * 64;
    const int col0 = blockIdx.y * 64;
    const int tid  = threadIdx.x;
    const int tr = tid >> 4;
    const int tc = tid & 15;

    float acc[4][4] = {};

    for (int k0 = 0; k0 < DM; k0 += 16) {
        #pragma unroll
        for (int u = 0; u < 4; ++u) {
            int e = tid + 256 * u;
            int r = e >> 4, c = e & 15;
            Xs[r][c] = x[(size_t)(row0 + r) * DM + k0 + c];
            Ws[r][c] = w[(size_t)(col0 + r) * DM + k0 + c];
        }
        __syncthreads();
        #pragma unroll
        for (int kk = 0; kk < 16; ++kk) {
            float a[4], b[4];
            #pragma unroll
            for (int i = 0; i < 4; ++i) a[i] = Xs[tr * 4 + i][kk];
            #pragma unroll
            for (int j = 0; j < 4; ++j) b[j] = Ws[tc * 4 + j][kk];
            #pragma unroll
            for (int i = 0; i < 4; ++i)
                #pragma unroll
                for (int j = 0; j < 4; ++j)
                    acc[i][j] += a[i] * b[j];
        }
        __syncthreads();
    }

    #pragma unroll
    for (int i = 0; i < 4; ++i) {
        int r = row0 + tr * 4 + i;
        #pragma unroll
        for (int j = 0; j < 4; ++j) {
            int c = col0 + tc * 4 + j;
            out[(size_t)r * DM + c] = acc[i][j] + bias[c];
        }
    }
}

// ---------------------------------------------------------------------------
// V transpose: vo [b][j][h*64+d] (= d_out scratch) -> vt [b][h][d][j]
// ---------------------------------------------------------------------------
__global__ __launch_bounds__(256) void transpose_v(
    const float* __restrict__ vo, float* __restrict__ vt)
{
    const int jt = blockIdx.x;   // 0..15 (64-j tile)
    const int h  = blockIdx.y;
    const int b  = blockIdx.z;
    const int tid = threadIdx.x;
    __shared__ float tile[64][65];

    for (int e = tid; e < 4096; e += 256) {
        int r = e >> 6, c = e & 63;
        tile[r][c] = vo[((size_t)(b * SEQ + jt * 64 + r)) * DM + h * HD + c];
    }
    __syncthreads();
    for (int e = tid; e < 4096; e += 256) {
        int d = e >> 6, jl = e & 63;
        vt[((size_t)(b * NH + h) * HD + d) * SEQ + jt * 64 + jl] = tile[jl][d];
    }
}

// ---------------------------------------------------------------------------
// MFMA attention. Block = (16-row i-tile, h, b), 4 waves.
// S[i,j] = q_i.k_j + q_i.demb[i-j+1023]; softmax(S/8); O = P V.
// ---------------------------------------------------------------------------
__global__ __launch_bounds__(256, 2) void attn_mfma(
    const float* __restrict__ qws, const float* __restrict__ kws,
    const float* __restrict__ vt,  const float* __restrict__ demb,
    float* __restrict__ out)
{
    const int i0 = blockIdx.x * 16;
    const int h  = blockIdx.y;
    const int b  = blockIdx.z;
    const int tid  = threadIdx.x;
    const int lane = tid & 63;
    const int w    = tid >> 6;      // wave 0..3
    const int lg   = lane >> 4;     // k-group 0..3
    const int lc   = lane & 15;     // row (A) / col (B,C/D) in tile
    const int d0   = lg * 8;

    __shared__ float S[16][1028];   // 65.8 KB: scores -> probabilities
    __shared__ float red[16][17];
    __shared__ float smInv[16];

    // Q A-fragments, held in registers for the whole score phase
    const float* qrow = qws + ((size_t)(b * SEQ + i0 + lc)) * DM + h * HD;
    const bf16x8 A0 = pack8(qrow + d0);
    const bf16x8 A1 = pack8(qrow + 32 + d0);

    const float* kbase = kws + ((size_t)(b * SEQ)) * DM + h * HD;

    // ---- score phase: wave w owns j in [w*256, w*256+256) ----
    for (int c = 0; c < 4; ++c) {
        const int jc = (w * 4 + c) * 64;
        const int rb = i0 - jc + 960;          // demb row base, in [0, 1968]
        f32x4 T[5];
        #pragma unroll
        for (int t = 0; t < 5; ++t) {
            const float* dp = demb + (size_t)(rb + t * 16 + lc) * HD;
            f32x4 acc = {0.f, 0.f, 0.f, 0.f};
            acc = MFMA(A0, pack8(dp + d0), acc);
            acc = MFMA(A1, pack8(dp + 32 + d0), acc);
            T[t] = acc;
        }
        #pragma unroll
        for (int jt = 0; jt < 4; ++jt) {
            const int j = jc + jt * 16 + lc;
            const float* kp = kbase + (size_t)j * DM;
            f32x4 s = {0.f, 0.f, 0.f, 0.f};
            s = MFMA(A0, pack8(kp + d0), s);
            s = MFMA(A1, pack8(kp + 32 + d0), s);
            // bias gather: S[row][j] += T[row][row - jl + 63]
            #pragma unroll
            for (int rr = 0; rr < 4; ++rr) {
                const int row  = lg * 4 + rr;
                const int roff = row + 63 - jt * 16 - lc;     // 0..78
                const int src  = (lane & 48) | (roff & 15);
                const int t    = roff >> 4;                   // 0..4
                float v0 = __shfl(T[0][rr], src, 64);
                float v1 = __shfl(T[1][rr], src, 64);
                float v2 = __shfl(T[2][rr], src, 64);
                float v3 = __shfl(T[3][rr], src, 64);
                float v4 = __shfl(T[4][rr], src, 64);
                float bias = (t == 0) ? v0 : (t == 1) ? v1 :
                             (t == 2) ? v2 : (t == 3) ? v3 : v4;
                S[row][j] = s[rr] + bias;
            }
        }
    }
    __syncthreads();

    // ---- softmax (scale AFTER bias add, factor 1/8) ----
    {
        const int row = tid >> 4;
        const int l   = tid & 15;
        float m = -1e30f;
        for (int j = l; j < SEQ; j += 16) m = fmaxf(m, S[row][j]);
        red[row][l] = m;
        __syncthreads();
        if (l == 0) {
            float mm = red[row][0];
            for (int t = 1; t < 16; ++t) mm = fmaxf(mm, red[row][t]);
            red[row][16] = mm;
        }
        __syncthreads();
        m = red[row][16];
        float sum = 0.f;
        for (int j = l; j < SEQ; j += 16) {
            float p = __expf((S[row][j] - m) * 0.125f);
            S[row][j] = p;
            sum += p;
        }
        red[row][l] = sum;
        __syncthreads();
        if (l == 0) {
            float ss = 0.f;
            for (int t = 0; t < 16; ++t) ss += red[row][t];
            smInv[row] = 1.0f / ss;
        }
        __syncthreads();
    }

    // ---- PV: wave w computes O[0:16][w*16 : w*16+16] over all j ----
    const float* vrow = vt + ((size_t)(b * NH + h) * HD + w * 16 + lc) * SEQ;
    f32x4 O = {0.f, 0.f, 0.f, 0.f};
    for (int jb = 0; jb < SEQ; jb += 32) {
        bf16x8 Af = pack8(&S[lc][jb + d0]);      // P rows from LDS
        bf16x8 Bf = pack8(vrow + jb + d0);       // V^T rows from global
        O = MFMA(Af, Bf, O);
    }
    #pragma unroll
    for (int rr = 0; rr < 4; ++rr) {
        const int row = lg * 4 + rr;
        out[((size_t)(b * SEQ + i0 + row)) * DM + h * HD + w * 16 + lc]
            = O[rr] * smInv[row];
    }
}

// ---------------------------------------------------------------------------
extern "C" void kernel_launch(void* const* d_in, const int* in_sizes, int n_in,
                              void* d_out, int out_size, void* d_ws, size_t ws_size,
                              hipStream_t stream) {
    const float* x  = (const float*)d_in[0];
    const float* wq = (const float*)d_in[1];
    const float* bq = (const float*)d_in[2];
    const float* wk = (const float*)d_in[3];
    const float* bk = (const float*)d_in[4];
    const float* wv = (const float*)d_in[5];
    const float* bv = (const float*)d_in[6];
    const float* de = (const float*)d_in[7];
    float* out = (float*)d_out;

    const size_t SL = (size_t)BATCH * SEQ * DM;   // 6,291,456
    float* ws  = (float*)d_ws;
    float* qws = ws;
    float* kws = ws + SL;
    float* vtw = ws + 2 * SL;
    float* vo  = out;    // stage raw V in d_out; fully overwritten by attn

    qkv_gemm<<<dim3(128, 12, 3), 256, 0, stream>>>(x, wq, bq, wk, bk, wv, bv,
                                                   qws, kws, vo);
    transpose_v<<<dim3(16, NH, BATCH), 256, 0, stream>>>(vo, vtw);
    attn_mfma<<<dim3(64, NH, BATCH), 256, 0, stream>>>(qws, kws, vtw, de, out);
}

// Round 6
// 660.818 us; speedup vs baseline: 6.6537x; 1.9661x over previous
//
#include <hip/hip_runtime.h>
#include <hip/hip_bf16.h>

#define NH 12
#define HD 64
#define DM 768
#define SEQ 1024
#define BATCH 8

typedef __attribute__((ext_vector_type(8))) short bf16x8;
typedef __attribute__((ext_vector_type(4))) short s16x4;
typedef __attribute__((ext_vector_type(4))) float f32x4;

__device__ __forceinline__ short f2b(float x) {
    unsigned u = __float_as_uint(x);
    u += 0x7fffu + ((u >> 16) & 1u);    // RNE to bf16 (finite values)
    return (short)(u >> 16);
}

// pack 8 consecutive f32 (LDS) into a bf16x8 MFMA fragment
__device__ __forceinline__ bf16x8 pack8(const float* p) {
    f32x4 a = *(const f32x4*)(p);
    f32x4 b = *(const f32x4*)(p + 4);
    bf16x8 r;
    r[0] = f2b(a[0]); r[1] = f2b(a[1]); r[2] = f2b(a[2]); r[3] = f2b(a[3]);
    r[4] = f2b(b[0]); r[5] = f2b(b[1]); r[6] = f2b(b[2]); r[7] = f2b(b[3]);
    return r;
}

#define MFMA(A, B, C) __builtin_amdgcn_mfma_f32_16x16x32_bf16(A, B, C, 0, 0, 0)

// ---------------------------------------------------------------------------
// f32 -> bf16 conversion (vectorized x4)
// ---------------------------------------------------------------------------
__global__ __launch_bounds__(256) void cvt_f32_bf16(
    const float* __restrict__ in, short* __restrict__ out, int n4)
{
    int i = blockIdx.x * 256 + threadIdx.x;
    if (i < n4) {
        f32x4 v = *(const f32x4*)(in + 4 * (size_t)i);
        s16x4 r;
        r[0] = f2b(v[0]); r[1] = f2b(v[1]); r[2] = f2b(v[2]); r[3] = f2b(v[3]);
        *(s16x4*)(out + 4 * (size_t)i) = r;
    }
}

// ---------------------------------------------------------------------------
// QKV projection, bf16 MFMA. out[i,o] = sum_d X[i,d]*W[o,d] + bias[o].
// Block = 64x64 output tile, 4 waves; wave w owns rows [w*16, w*16+16).
// Fragment conventions identical to the round-5-validated attn kernel:
//   A[row=lc][k=lg*8+e], B[col=lc][k=lg*8+e], D[row=lg*4+rr][col=lc].
// z==2 (V) writes the output TRANSPOSED into vt[b][h][d][j].
// ---------------------------------------------------------------------------
__global__ __launch_bounds__(256) void qkv_mfma(
    const short* __restrict__ xb,
    const short* __restrict__ wqb, const float* __restrict__ bq,
    const short* __restrict__ wkb, const float* __restrict__ bk,
    const short* __restrict__ wvb, const float* __restrict__ bv,
    short* __restrict__ qb, short* __restrict__ kb, short* __restrict__ vt)
{
    const short* wmat; const float* bias;
    const int z = blockIdx.z;
    if (z == 0)      { wmat = wqb; bias = bq; }
    else if (z == 1) { wmat = wkb; bias = bk; }
    else             { wmat = wvb; bias = bv; }

    const int i0   = blockIdx.x * 64;
    const int col0 = blockIdx.y * 64;
    const int lane = threadIdx.x & 63;
    const int w    = threadIdx.x >> 6;
    const int lg   = lane >> 4;
    const int lc   = lane & 15;
    const int d0   = lg * 8;

    const short* arow = xb + (size_t)(i0 + w * 16 + lc) * DM;

    f32x4 acc[4] = {};
    for (int k0 = 0; k0 < DM; k0 += 32) {
        bf16x8 a = *(const bf16x8*)(arow + k0 + d0);
        #pragma unroll
        for (int n = 0; n < 4; ++n) {
            const bf16x8 bfr = *(const bf16x8*)(
                wmat + (size_t)(col0 + n * 16 + lc) * DM + k0 + d0);
            acc[n] = MFMA(a, bfr, acc[n]);
        }
    }

    if (z < 2) {
        short* out = (z == 0) ? qb : kb;
        #pragma unroll
        for (int n = 0; n < 4; ++n) {
            const int c = col0 + n * 16 + lc;
            const float bi = bias[c];
            #pragma unroll
            for (int rr = 0; rr < 4; ++rr) {
                const int r = i0 + w * 16 + lg * 4 + rr;
                out[(size_t)r * DM + c] = f2b(acc[n][rr] + bi);
            }
        }
    } else {
        #pragma unroll
        for (int n = 0; n < 4; ++n) {
            const int c = col0 + n * 16 + lc;     // o = h*64 + d
            const int h = c >> 6, d = c & 63;
            const float bi = bias[c];
            #pragma unroll
            for (int rr = 0; rr < 4; ++rr) {
                const int r = i0 + w * 16 + lg * 4 + rr;   // b*1024 + j
                const int bb = r >> 10, j = r & 1023;
                vt[(((size_t)bb * NH + h) * HD + d) * SEQ + j] = f2b(acc[n][rr] + bi);
            }
        }
    }
}

// ---------------------------------------------------------------------------
// MFMA attention. Block = (16-row i-tile, h, b), 4 waves.
// S[i,j] = q_i.k_j + q_i.demb[i-j+1023]; softmax(S/8); O = P V.
// All operands bf16 in global; scores/probabilities f32 in LDS.
// ---------------------------------------------------------------------------
__global__ __launch_bounds__(256, 2) void attn_mfma(
    const short* __restrict__ qb, const short* __restrict__ kb,
    const short* __restrict__ vt, const short* __restrict__ deb,
    float* __restrict__ out)
{
    const int i0 = blockIdx.x * 16;
    const int h  = blockIdx.y;
    const int b  = blockIdx.z;
    const int tid  = threadIdx.x;
    const int lane = tid & 63;
    const int w    = tid >> 6;      // wave 0..3
    const int lg   = lane >> 4;     // k-group 0..3
    const int lc   = lane & 15;     // row (A) / col (B,C/D) in tile
    const int d0   = lg * 8;

    __shared__ float S[16][1028];   // 65.8 KB: scores -> probabilities
    __shared__ float red[16][17];
    __shared__ float smInv[16];

    // Q A-fragments in registers for the whole score phase
    const short* qrow = qb + ((size_t)(b * SEQ + i0 + lc)) * DM + h * HD;
    const bf16x8 A0 = *(const bf16x8*)(qrow + d0);
    const bf16x8 A1 = *(const bf16x8*)(qrow + 32 + d0);

    const short* kbase = kb + ((size_t)(b * SEQ)) * DM + h * HD;

    // ---- score phase: wave w owns j in [w*256, w*256+256) ----
    for (int c = 0; c < 4; ++c) {
        const int jc = (w * 4 + c) * 64;
        const int rb = i0 - jc + 960;          // demb row base, in [0, 1968]
        f32x4 T[5];                            // T[i][wrow]: bias table tiles
        #pragma unroll
        for (int t = 0; t < 5; ++t) {
            int drow = rb + t * 16 + lc;
            if (t == 4) drow = min(drow, 2046);       // col 79 unused; stay in-bounds
            const short* dp = deb + (size_t)drow * HD;
            f32x4 acc = {0.f, 0.f, 0.f, 0.f};
            acc = MFMA(A0, *(const bf16x8*)(dp + d0), acc);
            acc = MFMA(A1, *(const bf16x8*)(dp + 32 + d0), acc);
            T[t] = acc;
        }
        #pragma unroll
        for (int jt = 0; jt < 4; ++jt) {
            const int j = jc + jt * 16 + lc;
            const short* kp = kbase + (size_t)j * DM;
            f32x4 s = {0.f, 0.f, 0.f, 0.f};
            s = MFMA(A0, *(const bf16x8*)(kp + d0), s);
            s = MFMA(A1, *(const bf16x8*)(kp + 32 + d0), s);
            // bias gather: S[row][j] += T[row][row - jl + 63]
            #pragma unroll
            for (int rr = 0; rr < 4; ++rr) {
                const int row  = lg * 4 + rr;
                const int roff = row + 63 - jt * 16 - lc;     // in [tlo*16 .. ]
                const int src  = (lane & 48) | (roff & 15);
                // compile-time tile window: roff spans 27 -> 2 or 3 tiles
                const int tlo = (rr + 48 - jt * 16) >> 4;
                const int thi = (rr + 75 - jt * 16) >> 4;
                const int t   = roff >> 4;
                float c0 = __shfl(T[tlo][rr], src, 64);
                float c1 = __shfl(T[tlo + 1][rr], src, 64);
                float bias = (t == tlo) ? c0 : c1;
                if (tlo + 2 <= thi) {                         // folds at compile time
                    float c2 = __shfl(T[tlo + 2][rr], src, 64);
                    bias = (t == tlo + 2) ? c2 : bias;
                }
                S[row][j] = s[rr] + bias;
            }
        }
    }
    __syncthreads();

    // ---- softmax (scale AFTER bias add, factor 1/8) ----
    {
        const int row = tid >> 4;
        const int l   = tid & 15;
        float m = -1e30f;
        for (int j = l; j < SEQ; j += 16) m = fmaxf(m, S[row][j]);
        red[row][l] = m;
        __syncthreads();
        if (l == 0) {
            float mm = red[row][0];
            for (int t = 1; t < 16; ++t) mm = fmaxf(mm, red[row][t]);
            red[row][16] = mm;
        }
        __syncthreads();
        m = red[row][16];
        float sum = 0.f;
        for (int j = l; j < SEQ; j += 16) {
            float p = __expf((S[row][j] - m) * 0.125f);
            S[row][j] = p;
            sum += p;
        }
        red[row][l] = sum;
        __syncthreads();
        if (l == 0) {
            float ss = 0.f;
            for (int t = 0; t < 16; ++t) ss += red[row][t];
            smInv[row] = 1.0f / ss;
        }
        __syncthreads();
    }

    // ---- PV: wave w computes O[0:16][w*16 : w*16+16] over all j ----
    const short* vrow = vt + ((size_t)(b * NH + h) * HD + w * 16 + lc) * SEQ;
    f32x4 O = {0.f, 0.f, 0.f, 0.f};
    for (int jb = 0; jb < SEQ; jb += 32) {
        bf16x8 Af = pack8(&S[lc][jb + d0]);              // P rows from LDS (f32->bf16)
        bf16x8 Bf = *(const bf16x8*)(vrow + jb + d0);    // V^T rows, bf16 direct
        O = MFMA(Af, Bf, O);
    }
    #pragma unroll
    for (int rr = 0; rr < 4; ++rr) {
        const int row = lg * 4 + rr;
        out[((size_t)(b * SEQ + i0 + row)) * DM + h * HD + w * 16 + lc]
            = O[rr] * smInv[row];
    }
}

// ---------------------------------------------------------------------------
extern "C" void kernel_launch(void* const* d_in, const int* in_sizes, int n_in,
                              void* d_out, int out_size, void* d_ws, size_t ws_size,
                              hipStream_t stream) {
    const float* x  = (const float*)d_in[0];
    const float* wq = (const float*)d_in[1];
    const float* bq = (const float*)d_in[2];
    const float* wk = (const float*)d_in[3];
    const float* bk = (const float*)d_in[4];
    const float* wv = (const float*)d_in[5];
    const float* bv = (const float*)d_in[6];
    const float* de = (const float*)d_in[7];
    float* out = (float*)d_out;

    // bf16 workspace layout (~54 MB total, all 16B-aligned)
    const size_t NX = (size_t)BATCH * SEQ * DM;   // 6,291,456
    const size_t NW = (size_t)DM * DM;            //   589,824
    const size_t ND = 2047 * HD;                  //   131,008
    short* xb  = (short*)d_ws;
    short* wqb = xb  + NX;
    short* wkb = wqb + NW;
    short* wvb = wkb + NW;
    short* deb = wvb + NW;
    short* qbw = deb + ND;
    short* kbw = qbw + NX;
    short* vtw = kbw + NX;

    cvt_f32_bf16<<<(int)((NX / 4 + 255) / 256), 256, 0, stream>>>(x,  xb,  (int)(NX / 4));
    cvt_f32_bf16<<<(int)((NW / 4 + 255) / 256), 256, 0, stream>>>(wq, wqb, (int)(NW / 4));
    cvt_f32_bf16<<<(int)((NW / 4 + 255) / 256), 256, 0, stream>>>(wk, wkb, (int)(NW / 4));
    cvt_f32_bf16<<<(int)((NW / 4 + 255) / 256), 256, 0, stream>>>(wv, wvb, (int)(NW / 4));
    cvt_f32_bf16<<<(int)((ND / 4 + 255) / 256), 256, 0, stream>>>(de, deb, (int)(ND / 4));

    qkv_mfma<<<dim3(128, 12, 3), 256, 0, stream>>>(xb, wqb, bq, wkb, bk, wvb, bv,
                                                   qbw, kbw, vtw);
    attn_mfma<<<dim3(64, NH, BATCH), 256, 0, stream>>>(qbw, kbw, vtw, deb, out);
}

// Round 7
// 373.216 us; speedup vs baseline: 11.7811x; 1.7706x over previous
//
#include <hip/hip_runtime.h>
#include <hip/hip_bf16.h>

#define NH 12
#define HD 64
#define DM 768
#define SEQ 1024
#define BATCH 8

typedef __attribute__((ext_vector_type(8))) short bf16x8;
typedef __attribute__((ext_vector_type(4))) short s16x4;
typedef __attribute__((ext_vector_type(4))) float f32x4;

__device__ __forceinline__ short f2b(float x) {
    unsigned u = __float_as_uint(x);
    u += 0x7fffu + ((u >> 16) & 1u);    // RNE to bf16 (finite values)
    return (short)(u >> 16);
}

#define MFMA(A, B, C) __builtin_amdgcn_mfma_f32_16x16x32_bf16(A, B, C, 0, 0, 0)

// ---------------------------------------------------------------------------
// f32 -> bf16 conversion (vectorized x4)
// ---------------------------------------------------------------------------
__global__ __launch_bounds__(256) void cvt_f32_bf16(
    const float* __restrict__ in, short* __restrict__ out, int n4)
{
    int i = blockIdx.x * 256 + threadIdx.x;
    if (i < n4) {
        f32x4 v = *(const f32x4*)(in + 4 * (size_t)i);
        s16x4 r;
        r[0] = f2b(v[0]); r[1] = f2b(v[1]); r[2] = f2b(v[2]); r[3] = f2b(v[3]);
        *(s16x4*)(out + 4 * (size_t)i) = r;
    }
}

// ---------------------------------------------------------------------------
// QKV projection, bf16 MFMA with coalesced LDS staging.
// 64x64 output tile, BK=64, padded LDS [64][72] (2-way banks = free).
// 1D grid 4608 = 36*(y,z) x 128(bx), XCD-swizzled; consecutive ids share bx.
// z==2 (V) scatters output transposed into vt[b][h][d][j].
// ---------------------------------------------------------------------------
__global__ __launch_bounds__(256, 4) void qkv_mfma(
    const short* __restrict__ xb,
    const short* __restrict__ wqb, const float* __restrict__ bq,
    const short* __restrict__ wkb, const float* __restrict__ bk,
    const short* __restrict__ wvb, const float* __restrict__ bv,
    short* __restrict__ qb, short* __restrict__ kb, short* __restrict__ vt)
{
    __shared__ short Xl[64][72];
    __shared__ short Wl[64][72];

    const int orig = blockIdx.x;                 // 4608 blocks, 4608%8==0
    const int sw   = (orig & 7) * 576 + (orig >> 3);
    const int t    = sw % 36;
    const int by   = t % 12;
    const int z    = t / 12;
    const int bx   = sw / 36;

    const short* wmat = (z == 0) ? wqb : (z == 1) ? wkb : wvb;
    const float* bias = (z == 0) ? bq : (z == 1) ? bk : bv;

    const int i0   = bx * 64;
    const int col0 = by * 64;
    const int tid  = threadIdx.x;
    const int lane = tid & 63;
    const int w    = tid >> 6;
    const int lg   = lane >> 4;
    const int lc   = lane & 15;

    f32x4 acc[4] = {};
    for (int k0 = 0; k0 < DM; k0 += 64) {
        __syncthreads();    // protect Xl/Wl reuse
        #pragma unroll
        for (int e = tid; e < 512; e += 256) {
            const int r = e >> 3, c8 = e & 7;
            *(bf16x8*)&Xl[r][c8 * 8] =
                *(const bf16x8*)&xb[(size_t)(i0 + r) * DM + k0 + c8 * 8];
            *(bf16x8*)&Wl[r][c8 * 8] =
                *(const bf16x8*)&wmat[(size_t)(col0 + r) * DM + k0 + c8 * 8];
        }
        __syncthreads();
        #pragma unroll
        for (int kh = 0; kh < 2; ++kh) {
            const bf16x8 a = *(const bf16x8*)&Xl[w * 16 + lc][kh * 32 + lg * 8];
            #pragma unroll
            for (int n = 0; n < 4; ++n) {
                const bf16x8 bfr = *(const bf16x8*)&Wl[n * 16 + lc][kh * 32 + lg * 8];
                acc[n] = MFMA(a, bfr, acc[n]);
            }
        }
    }

    if (z < 2) {
        short* outp = (z == 0) ? qb : kb;
        #pragma unroll
        for (int n = 0; n < 4; ++n) {
            const int c = col0 + n * 16 + lc;
            const float bi = bias[c];
            #pragma unroll
            for (int rr = 0; rr < 4; ++rr) {
                const int r = i0 + w * 16 + lg * 4 + rr;
                outp[(size_t)r * DM + c] = f2b(acc[n][rr] + bi);
            }
        }
    } else {
        #pragma unroll
        for (int n = 0; n < 4; ++n) {
            const int c = col0 + n * 16 + lc;     // o = h*64 + d
            const int h = c >> 6, d = c & 63;
            const float bi = bias[c];
            #pragma unroll
            for (int rr = 0; rr < 4; ++rr) {
                const int r  = i0 + w * 16 + lg * 4 + rr;   // b*1024 + j
                const int bb = r >> 10, j = r & 1023;
                vt[(((size_t)bb * NH + h) * HD + d) * SEQ + j] = f2b(acc[n][rr] + bi);
            }
        }
    }
}

// ---------------------------------------------------------------------------
// Flash-style MFMA attention with relative-key bias.
// Block = 32 Q-rows x (h,b), 8 waves (512 thr). j-chunks of 128.
// Wave w: rt = w>>2 (row-tile), js = w&3 (j-subchunk for QK / d-slice for PV).
// Per chunk: stage K[128][72], demb-window[159][72] (coalesced, padded);
// T[32][0..158] = Q . demb^T into LDS f32; S = QK + T-gather; block-wide
// online softmax (m,l in regs, stats via LDS); P bf16 in LDS; PV d-sliced.
// 3 barriers/chunk; next chunk staged during exp phase.
// ---------------------------------------------------------------------------
__global__ __launch_bounds__(512, 4) void attn_flash(
    const short* __restrict__ qb, const short* __restrict__ kb,
    const short* __restrict__ vt, const short* __restrict__ deb,
    float* __restrict__ out)
{
    const int orig = blockIdx.x;                 // 3072 blocks, 3072%8==0
    const int sw   = (orig & 7) * 384 + (orig >> 3);   // XCD gets one batch
    const int bx   = sw & 31;
    const int h    = (sw >> 5) % NH;
    const int b    = sw / (32 * NH);

    const int i0   = bx * 32;
    const int tid  = threadIdx.x;
    const int lane = tid & 63;
    const int w    = tid >> 6;        // 0..7
    const int rt   = w >> 2;          // row-tile 0..1
    const int js   = w & 3;           // j-subchunk / d-slice
    const int lg   = lane >> 4;
    const int lc   = lane & 15;

    __shared__ short Kl[128][72];     // 18.0 KB
    __shared__ short Dl[160][72];     // 22.5 KB (159 rows staged)
    __shared__ float Tl[32][168];     // 21.0 KB (cols 0..158 valid)
    __shared__ short Pl[32][136];     // 8.5 KB
    __shared__ float maxp[4][32];
    __shared__ float sump[4][32];

    // Q fragments for this wave's row-tile (held whole kernel)
    const short* qrow = qb + ((size_t)(b * SEQ + i0 + rt * 16 + lc)) * DM + h * HD;
    const bf16x8 A0 = *(const bf16x8*)(qrow + lg * 8);
    const bf16x8 A1 = *(const bf16x8*)(qrow + 32 + lg * 8);

    const short* kbase = kb + ((size_t)(b * SEQ)) * DM + h * HD;
    const short* vbase = vt + ((size_t)(b * NH + h) * HD + js * 16 + lc) * SEQ;

    auto stage = [&](int jc) {
        for (int e = tid; e < 128 * 8; e += 512) {           // K chunk
            const int r = e >> 3, c8 = e & 7;
            *(bf16x8*)&Kl[r][c8 * 8] =
                *(const bf16x8*)&kbase[(size_t)(jc + r) * DM + c8 * 8];
        }
        const int wb = i0 - jc + 896;                        // demb window base
        for (int e = tid; e < 159 * 8; e += 512) {
            const int r = e >> 3, c8 = e & 7;
            *(bf16x8*)&Dl[r][c8 * 8] =
                *(const bf16x8*)&deb[(size_t)(wb + r) * HD + c8 * 8];
        }
    };

    float m[4], l[4];
    f32x4 O = {0.f, 0.f, 0.f, 0.f};
    #pragma unroll
    for (int rr = 0; rr < 4; ++rr) { m[rr] = -1e30f; l[rr] = 0.f; }

    stage(0);
    __syncthreads();

    for (int c = 0; c < 8; ++c) {
        const int jc = c * 128;

        // ---- T tiles (rt rows; ct2 = js, js+4, js+8) + QK from LDS ----
        #pragma unroll
        for (int tt = 0; tt < 3; ++tt) {
            const int ct2 = js + tt * 4;
            if (ct2 < 10) {
                f32x4 a = {0.f, 0.f, 0.f, 0.f};
                a = MFMA(A0, *(const bf16x8*)&Dl[ct2 * 16 + lc][lg * 8], a);
                a = MFMA(A1, *(const bf16x8*)&Dl[ct2 * 16 + lc][32 + lg * 8], a);
                #pragma unroll
                for (int rr = 0; rr < 4; ++rr)
                    Tl[rt * 16 + lg * 4 + rr][ct2 * 16 + lc] = a[rr];
            }
        }
        f32x4 s0 = {0.f, 0.f, 0.f, 0.f}, s1 = {0.f, 0.f, 0.f, 0.f};
        {
            const int j0 = js * 32;
            s0 = MFMA(A0, *(const bf16x8*)&Kl[j0 + lc][lg * 8], s0);
            s0 = MFMA(A1, *(const bf16x8*)&Kl[j0 + lc][32 + lg * 8], s0);
            s1 = MFMA(A0, *(const bf16x8*)&Kl[j0 + 16 + lc][lg * 8], s1);
            s1 = MFMA(A1, *(const bf16x8*)&Kl[j0 + 16 + lc][32 + lg * 8], s1);
        }
        __syncthreads();   // bar1: Tl ready; Kl/Dl reads done

        // ---- bias add (Tl gather) + chunk row-max ----
        float sv[2][4];
        #pragma unroll
        for (int jt = 0; jt < 2; ++jt)
            #pragma unroll
            for (int rr = 0; rr < 4; ++rr) {
                const int row = rt * 16 + lg * 4 + rr;
                const int jl  = js * 32 + jt * 16 + lc;
                sv[jt][rr] = (jt ? s1[rr] : s0[rr]) + Tl[row][row - jl + 127];
            }
        #pragma unroll
        for (int rr = 0; rr < 4; ++rr) {
            float mw = fmaxf(sv[0][rr], sv[1][rr]);
            mw = fmaxf(mw, __shfl_xor(mw, 1, 64));
            mw = fmaxf(mw, __shfl_xor(mw, 2, 64));
            mw = fmaxf(mw, __shfl_xor(mw, 4, 64));
            mw = fmaxf(mw, __shfl_xor(mw, 8, 64));
            if (lc == 0) maxp[js][rt * 16 + lg * 4 + rr] = mw;
        }
        __syncthreads();   // bar2: maxp ready

        // ---- m_new, exp, partial sums, P write; stage next chunk ----
        float scale[4];
        #pragma unroll
        for (int rr = 0; rr < 4; ++rr) {
            const int row = rt * 16 + lg * 4 + rr;
            float mn = m[rr];
            mn = fmaxf(mn, maxp[0][row]);
            mn = fmaxf(mn, maxp[1][row]);
            mn = fmaxf(mn, maxp[2][row]);
            mn = fmaxf(mn, maxp[3][row]);
            scale[rr] = __expf((m[rr] - mn) * 0.125f);
            m[rr] = mn;
            float ps = 0.f;
            #pragma unroll
            for (int jt = 0; jt < 2; ++jt) {
                const float p = __expf((sv[jt][rr] - mn) * 0.125f);
                Pl[row][js * 32 + jt * 16 + lc] = f2b(p);
                ps += p;
            }
            ps += __shfl_xor(ps, 1, 64);
            ps += __shfl_xor(ps, 2, 64);
            ps += __shfl_xor(ps, 4, 64);
            ps += __shfl_xor(ps, 8, 64);
            if (lc == 0) sump[js][row] = ps;
        }
        if (c < 7) stage(jc + 128);
        __syncthreads();   // bar3: Pl/sump ready; next-chunk staging landed

        // ---- l update, O rescale, PV (d-slice js) ----
        #pragma unroll
        for (int rr = 0; rr < 4; ++rr) {
            const int row = rt * 16 + lg * 4 + rr;
            l[rr] = l[rr] * scale[rr]
                  + sump[0][row] + sump[1][row] + sump[2][row] + sump[3][row];
            O[rr] *= scale[rr];
        }
        #pragma unroll
        for (int ks = 0; ks < 4; ++ks) {
            const bf16x8 Af = *(const bf16x8*)&Pl[rt * 16 + lc][ks * 32 + lg * 8];
            const bf16x8 Bf = *(const bf16x8*)&vbase[jc + ks * 32 + lg * 8];
            O = MFMA(Af, Bf, O);
        }
    }

    #pragma unroll
    for (int rr = 0; rr < 4; ++rr) {
        const int row = i0 + rt * 16 + lg * 4 + rr;
        out[((size_t)(b * SEQ + row)) * DM + h * HD + js * 16 + lc] = O[rr] / l[rr];
    }
}

// ---------------------------------------------------------------------------
extern "C" void kernel_launch(void* const* d_in, const int* in_sizes, int n_in,
                              void* d_out, int out_size, void* d_ws, size_t ws_size,
                              hipStream_t stream) {
    const float* x  = (const float*)d_in[0];
    const float* wq = (const float*)d_in[1];
    const float* bq = (const float*)d_in[2];
    const float* wk = (const float*)d_in[3];
    const float* bk = (const float*)d_in[4];
    const float* wv = (const float*)d_in[5];
    const float* bv = (const float*)d_in[6];
    const float* de = (const float*)d_in[7];
    float* out = (float*)d_out;

    // bf16 workspace layout (~58 MB total, all 16B-aligned)
    const size_t NX = (size_t)BATCH * SEQ * DM;   // 6,291,456
    const size_t NW = (size_t)DM * DM;            //   589,824
    const size_t ND = 2047 * HD;                  //   131,008
    short* xb  = (short*)d_ws;
    short* wqb = xb  + NX;
    short* wkb = wqb + NW;
    short* wvb = wkb + NW;
    short* deb = wvb + NW;
    short* qbw = deb + ND;
    short* kbw = qbw + NX;
    short* vtw = kbw + NX;

    cvt_f32_bf16<<<(int)((NX / 4 + 255) / 256), 256, 0, stream>>>(x,  xb,  (int)(NX / 4));
    cvt_f32_bf16<<<(int)((NW / 4 + 255) / 256), 256, 0, stream>>>(wq, wqb, (int)(NW / 4));
    cvt_f32_bf16<<<(int)((NW / 4 + 255) / 256), 256, 0, stream>>>(wk, wkb, (int)(NW / 4));
    cvt_f32_bf16<<<(int)((NW / 4 + 255) / 256), 256, 0, stream>>>(wv, wvb, (int)(NW / 4));
    cvt_f32_bf16<<<(int)((ND / 4 + 255) / 256), 256, 0, stream>>>(de, deb, (int)(ND / 4));

    qkv_mfma<<<4608, 256, 0, stream>>>(xb, wqb, bq, wkb, bk, wvb, bv,
                                       qbw, kbw, vtw);
    attn_flash<<<3072, 512, 0, stream>>>(qbw, kbw, vtw, deb, out);
}